// Round 2
// baseline (320.708 us; speedup 1.0000x reference)
//
#include <hip/hip_runtime.h>

#define PGRID 576      // H*W
#define NB0   64
#define NBTOT 128
#define CIN   256
#define KNN   9
#define NNODE (NB0 * PGRID)   // 36864

// ---------------------------------------------------------------------------
// K1: h = node @ W_space   (A is x[:64] read in NHWC-gather order)
// A[n][c] = x[b*CIN*P + c*P + p], n = b*P + p.  64x64x64 tiles, 4x4 microtile.
// ---------------------------------------------------------------------------
__global__ __launch_bounds__(256) void gemm_space(const float* __restrict__ x,
                                                  const float* __restrict__ Wsp,
                                                  float* __restrict__ h) {
    __shared__ float As[64][65];
    __shared__ float Bs[64][65];
    const int n0 = blockIdx.x * 64;          // row tile (same image: 576 % 64 == 0)
    const int j0 = blockIdx.y * 64;          // col tile
    const int b  = n0 / PGRID;
    const int p0 = n0 % PGRID;
    const int t  = threadIdx.x;
    const int tx = t % 16, ty = t / 16;
    const int cl = t / 64, pl = t % 64;
    const float* xb = x + (size_t)b * CIN * PGRID;

    float acc[4][4] = {};
    for (int c0 = 0; c0 < CIN; c0 += 64) {
#pragma unroll
        for (int r = 0; r < 16; ++r) {
            int c = c0 + r * 4 + cl;
            As[r * 4 + cl][pl] = xb[c * PGRID + p0 + pl];
            Bs[r * 4 + cl][pl] = Wsp[c * 256 + j0 + pl];
        }
        __syncthreads();
#pragma unroll
        for (int kk = 0; kk < 64; ++kk) {
            float a[4], bb[4];
#pragma unroll
            for (int i = 0; i < 4; ++i) a[i] = As[kk][ty * 4 + i];
#pragma unroll
            for (int j = 0; j < 4; ++j) bb[j] = Bs[kk][tx * 4 + j];
#pragma unroll
            for (int i = 0; i < 4; ++i)
#pragma unroll
                for (int j = 0; j < 4; ++j) acc[i][j] += a[i] * bb[j];
        }
        __syncthreads();
    }
#pragma unroll
    for (int i = 0; i < 4; ++i) {
        int n = n0 + ty * 4 + i;
#pragma unroll
        for (int j = 0; j < 4; ++j)
            h[(size_t)n * 256 + j0 + tx * 4 + j] = acc[i][j];
    }
}

// ---------------------------------------------------------------------------
// K2: attention scores a_s[n,h], a_d[n,h]  (one wave per node)
// ---------------------------------------------------------------------------
__global__ __launch_bounds__(256) void att_scores(const float* __restrict__ h,
                                                  const float* __restrict__ att_src,
                                                  const float* __restrict__ att_dst,
                                                  float* __restrict__ as_,
                                                  float* __restrict__ ad_) {
    const int wave = threadIdx.x >> 6;
    const int lane = threadIdx.x & 63;
    const int n = blockIdx.x * 4 + wave;
    const float* hr = h + (size_t)n * 256;
    float h0 = hr[lane], h1 = hr[lane + 64], h2 = hr[lane + 128], h3 = hr[lane + 192];
    float s0 = h0 * att_src[lane]      + h1 * att_src[lane + 64];
    float s1 = h2 * att_src[lane + 128] + h3 * att_src[lane + 192];
    float d0 = h0 * att_dst[lane]      + h1 * att_dst[lane + 64];
    float d1 = h2 * att_dst[lane + 128] + h3 * att_dst[lane + 192];
#pragma unroll
    for (int off = 32; off > 0; off >>= 1) {
        s0 += __shfl_down(s0, off);
        s1 += __shfl_down(s1, off);
        d0 += __shfl_down(d0, off);
        d1 += __shfl_down(d1, off);
    }
    if (lane == 0) {
        as_[n * 2] = s0; as_[n * 2 + 1] = s1;
        ad_[n * 2] = d0; ad_[n * 2 + 1] = d1;
    }
}

// ---------------------------------------------------------------------------
// K3: space GAT gather. dst n has edges at slots n*9..n*9+8 plus self loop.
// ---------------------------------------------------------------------------
__global__ __launch_bounds__(256) void space_gather(const float* __restrict__ h,
                                                    const float* __restrict__ as_,
                                                    const float* __restrict__ ad_,
                                                    const int* __restrict__ esrc,
                                                    const float* __restrict__ bias,
                                                    float* __restrict__ xs) {
    __shared__ int   s_src[10];
    __shared__ float s_e[10][2];
    const int n = blockIdx.x;
    const int t = threadIdx.x;
    if (t < 10) {
        int src = (t < 9) ? esrc[(size_t)n * KNN + t] : n;
        s_src[t] = src;
        float ad0 = ad_[n * 2], ad1 = ad_[n * 2 + 1];
        float e0 = as_[src * 2]     + ad0;
        float e1 = as_[src * 2 + 1] + ad1;
        s_e[t][0] = e0 >= 0.f ? e0 : 0.2f * e0;
        s_e[t][1] = e1 >= 0.f ? e1 : 0.2f * e1;
    }
    __syncthreads();
    const int head = t >> 7;
    float m = -1e30f;
#pragma unroll
    for (int k = 0; k < 10; ++k) m = fmaxf(m, s_e[k][head]);
    float w[10];
    float ssum = 0.f;
#pragma unroll
    for (int k = 0; k < 10; ++k) { w[k] = __expf(s_e[k][head] - m); ssum += w[k]; }
    const float inv = 1.f / (ssum + 1e-16f);
    float out = 0.f;
#pragma unroll
    for (int k = 0; k < 10; ++k) out += w[k] * h[(size_t)s_src[k] * 256 + t];
    xs[(size_t)n * 256 + t] = out * inv + bias[t];
}

// ---------------------------------------------------------------------------
// K4: emb[b] = mean over 576 patches of x_space
// ---------------------------------------------------------------------------
__global__ __launch_bounds__(256) void pool_emb(const float* __restrict__ xs,
                                                float* __restrict__ emb) {
    const int b = blockIdx.x, j = threadIdx.x;
    const float* base = xs + (size_t)b * PGRID * 256 + j;
    float s = 0.f;
    for (int p = 0; p < PGRID; ++p) s += base[p * 256];
    emb[b * 256 + j] = s * (1.f / 576.f);
}

// ---------------------------------------------------------------------------
// K5: h_view[i] = emb[i%64] @ W_view ; scalar attn scores per node
// ---------------------------------------------------------------------------
__global__ __launch_bounds__(256) void view_linear(const float* __restrict__ emb,
                                                   const float* __restrict__ Wv,
                                                   const float* __restrict__ att_s,
                                                   const float* __restrict__ att_d,
                                                   float* __restrict__ hv,
                                                   float* __restrict__ asv,
                                                   float* __restrict__ adv) {
    __shared__ float er[256];
    __shared__ float red[2][256];
    const int i = blockIdx.x;       // 0..127
    const int j = threadIdx.x;
    er[j] = emb[(i % 64) * 256 + j];
    __syncthreads();
    float acc = 0.f;
    for (int c = 0; c < 256; ++c) acc += er[c] * Wv[c * 256 + j];
    hv[(size_t)i * 256 + j] = acc;
    red[0][j] = acc * att_s[j];
    red[1][j] = acc * att_d[j];
    __syncthreads();
    for (int off = 128; off > 0; off >>= 1) {
        if (j < off) { red[0][j] += red[0][j + off]; red[1][j] += red[1][j + off]; }
        __syncthreads();
    }
    if (j == 0) { asv[i] = red[0][0]; adv[i] = red[1][0]; }
}

// ---------------------------------------------------------------------------
// K6: view GAT gather for dst 0..63 (only feat[:64] consumed).
// ---------------------------------------------------------------------------
__global__ __launch_bounds__(256) void view_gather(const float* __restrict__ hv,
                                                   const float* __restrict__ asv,
                                                   const float* __restrict__ adv,
                                                   const int* __restrict__ ev,
                                                   int Ev,
                                                   const float* __restrict__ bias,
                                                   float* __restrict__ feat) {
    __shared__ int cnt;
    __shared__ int s_src[32];
    const int d = blockIdx.x;   // 0..63
    const int t = threadIdx.x;
    if (t == 0) cnt = 0;
    __syncthreads();
    for (int e = t; e < Ev; e += 256) {
        if (ev[Ev + e] == d) {
            int pos = atomicAdd(&cnt, 1);
            s_src[pos] = ev[e];
        }
    }
    __syncthreads();
    const int ns = cnt;   // <= 15
    const float adval = adv[d];
    float m = -1e30f;
    float ev_[16];
#pragma unroll 1
    for (int k = 0; k < ns; ++k) {
        float e = asv[s_src[k]] + adval;
        e = e >= 0.f ? e : 0.2f * e;
        ev_[k] = e;
        m = fmaxf(m, e);
    }
    float eself = asv[d] + adval;
    eself = eself >= 0.f ? eself : 0.2f * eself;
    m = fmaxf(m, eself);
    float ssum = 0.f;
#pragma unroll 1
    for (int k = 0; k < ns; ++k) { ev_[k] = __expf(ev_[k] - m); ssum += ev_[k]; }
    float wself = __expf(eself - m);
    ssum += wself;
    const float inv = 1.f / (ssum + 1e-16f);
    float out = 0.f;
#pragma unroll 1
    for (int k = 0; k < ns; ++k) out += ev_[k] * hv[(size_t)s_src[k] * 256 + t];
    out += wself * hv[(size_t)d * 256 + t];
    feat[d * 256 + t] = out * inv + bias[t];
}

// ---------------------------------------------------------------------------
// K7: out = 0.5*x_space + 0.5*feat[b]  (flat reinterpret layout)
// ---------------------------------------------------------------------------
__global__ __launch_bounds__(256) void combine(const float* __restrict__ xs,
                                               const float* __restrict__ feat,
                                               float* __restrict__ out, int ntot4) {
    int i = blockIdx.x * blockDim.x + threadIdx.x;
    if (i >= ntot4) return;
    size_t f = (size_t)i * 4;
    int b = (int)(f / (PGRID * 256));
    int j = (int)(f & 255);
    float4 a  = *(const float4*)(xs + f);
    float4 fb = *(const float4*)(feat + b * 256 + j);
    float4 o;
    o.x = 0.5f * (a.x + fb.x);
    o.y = 0.5f * (a.y + fb.y);
    o.z = 0.5f * (a.z + fb.z);
    o.w = 0.5f * (a.w + fb.w);
    *(float4*)(out + f) = o;
}

// ---------------------------------------------------------------------------
extern "C" void kernel_launch(void* const* d_in, const int* in_sizes, int n_in,
                              void* d_out, int out_size, void* d_ws, size_t ws_size,
                              hipStream_t stream) {
    const float* x        = (const float*)d_in[0];
    const int*   e_space  = (const int*)d_in[3];   // [2, Es] int32 (harness converts)
    const int*   e_view   = (const int*)d_in[4];   // [2, Ev] int32
    const float* W_space  = (const float*)d_in[5];
    const float* att_ss   = (const float*)d_in[6];
    const float* att_ds   = (const float*)d_in[7];
    const float* bias_s   = (const float*)d_in[8];
    const float* W_view   = (const float*)d_in[9];
    const float* att_sv   = (const float*)d_in[10];
    const float* att_dv   = (const float*)d_in[11];
    const float* bias_v   = (const float*)d_in[12];
    float* out = (float*)d_out;

    const int Ev = in_sizes[4] / 2;

    // workspace layout (floats)
    float* ws   = (float*)d_ws;
    float* h    = ws;                         // 36864*256
    float* xs   = h    + (size_t)NNODE * 256; // 36864*256
    float* as_  = xs   + (size_t)NNODE * 256; // 36864*2
    float* ad_  = as_  + NNODE * 2;
    float* emb  = ad_  + NNODE * 2;           // 64*256
    float* hv   = emb  + 64 * 256;            // 128*256
    float* asv  = hv   + 128 * 256;           // 128
    float* adv  = asv  + 128;                 // 128
    float* feat = adv  + 128;                 // 64*256

    gemm_space<<<dim3(NNODE / 64, 4), 256, 0, stream>>>(x, W_space, h);
    att_scores<<<NNODE / 4, 256, 0, stream>>>(h, att_ss, att_ds, as_, ad_);
    space_gather<<<NNODE, 256, 0, stream>>>(h, as_, ad_, e_space, bias_s, xs);
    pool_emb<<<NB0, 256, 0, stream>>>(xs, emb);
    view_linear<<<NBTOT, 256, 0, stream>>>(emb, W_view, att_sv, att_dv, hv, asv, adv);
    view_gather<<<NB0, 256, 0, stream>>>(hv, asv, adv, e_view, Ev, bias_v, feat);

    const int ntot4 = NB0 * PGRID * 256 / 4;
    combine<<<(ntot4 + 255) / 256, 256, 0, stream>>>(xs, feat, out, ntot4);
}

// Round 3
// 242.233 us; speedup vs baseline: 1.3240x; 1.3240x over previous
//
#include <hip/hip_runtime.h>

#define PGRID 576
#define NB0   64
#define NBTOT 128
#define CIN   256
#define KNN   9
#define NNODE (NB0 * PGRID)   // 36864

typedef __attribute__((ext_vector_type(8))) short short8;
typedef __attribute__((ext_vector_type(4))) float f32x4;

__device__ __forceinline__ float bf2f(unsigned short u) {
    union { unsigned int i; float f; } v; v.i = ((unsigned int)u) << 16; return v.f;
}
__device__ __forceinline__ unsigned short f2b(float f) {
    unsigned int u = __float_as_uint(f);
    return (unsigned short)((u + 0x7FFFu + ((u >> 16) & 1u)) >> 16);
}

// ---------------------------------------------------------------------------
// P1: Wt[j][c] = bf16(W[c][j])   (j-major, c contiguous)
// ---------------------------------------------------------------------------
__global__ __launch_bounds__(256) void prep_w(const float* __restrict__ W,
                                              unsigned short* __restrict__ Wt) {
    __shared__ float tile[64][65];
    const int c0 = blockIdx.x * 64, j0 = blockIdx.y * 64;
    const int t = threadIdx.x, lo = t % 64, hi = t / 64;
#pragma unroll
    for (int r = 0; r < 16; ++r)
        tile[r * 4 + hi][lo] = W[(size_t)(c0 + r * 4 + hi) * 256 + j0 + lo];
    __syncthreads();
#pragma unroll
    for (int r = 0; r < 16; ++r)
        Wt[(size_t)(j0 + r * 4 + hi) * 256 + c0 + lo] = f2b(tile[lo][r * 4 + hi]);
}

// ---------------------------------------------------------------------------
// P2: xbf[n][c] = bf16(x[b,c,p]),  n = b*576 + p   (c contiguous)
// ---------------------------------------------------------------------------
__global__ __launch_bounds__(256) void prep_x(const float* __restrict__ x,
                                              unsigned short* __restrict__ xbf) {
    __shared__ float tile[64][65];
    const int pt = blockIdx.x, ct = blockIdx.y, b = blockIdx.z;
    const int t = threadIdx.x, lo = t % 64, hi = t / 64;
    const float* xb = x + (size_t)b * CIN * PGRID;
#pragma unroll
    for (int r = 0; r < 16; ++r)
        tile[r * 4 + hi][lo] = xb[(size_t)(ct * 64 + r * 4 + hi) * PGRID + pt * 64 + lo];
    __syncthreads();
    const size_t nbase = (size_t)b * PGRID + pt * 64;
#pragma unroll
    for (int r = 0; r < 16; ++r)
        xbf[(nbase + r * 4 + hi) * 256 + ct * 64 + lo] = f2b(tile[lo][r * 4 + hi]);
}

// ---------------------------------------------------------------------------
// K1: h[n][j] = bf16( xbf[n][:] @ Wt[j][:] )  via mfma_f32_16x16x32_bf16.
// BM=BN=64, full K=256 panels in LDS (64KB), single barrier.
// LDS layout: A[row][chunk^(row&7)] via pre-swizzled global_load_lds source.
// ---------------------------------------------------------------------------
__global__ __launch_bounds__(256) void gemm_mfma(const unsigned short* __restrict__ xbf,
                                                 const unsigned short* __restrict__ Wt,
                                                 unsigned short* __restrict__ h) {
    __shared__ char lds[65536];            // A: 0..32767, B: 32768..65535
    const int t  = threadIdx.x;
    const int n0 = blockIdx.x * 64;
    const int j0 = blockIdx.y * 64;
    const char* Ab = (const char*)xbf + (size_t)n0 * 512;
    const char* Bb = (const char*)Wt  + (size_t)j0 * 512;

    // stage: 64 rows x 512B each for A and B; 8 passes of 4KB each.
#pragma unroll
    for (int pass = 0; pass < 8; ++pass) {
        const int p    = pass * 4096 + t * 16;    // byte pos in panel
        const int row  = p >> 9;
        const int k16  = (p >> 4) & 31;
        const int src  = k16 ^ (row & 7);
        char* ldA = lds + pass * 4096 + (t & 192) * 16;          // wave-uniform
        char* ldB = ldA + 32768;
        __builtin_amdgcn_global_load_lds(Ab + (size_t)row * 512 + src * 16, ldA, 16, 0, 0);
        __builtin_amdgcn_global_load_lds(Bb + (size_t)row * 512 + src * 16, ldB, 16, 0, 0);
    }
    __syncthreads();

    const int l  = t & 63, w = t >> 6;
    const int qb = l >> 4;            // lane group 0..3
    const int r7 = l & 7;
    const int rowA = w * 16 + (l & 15);
    const char* lA = lds + rowA * 512;
    f32x4 acc[4] = {};
#pragma unroll
    for (int ks = 0; ks < 8; ++ks) {
        const int q = (ks << 2) + qb;
        short8 a = *(const short8*)(lA + ((q ^ r7) << 4));
#pragma unroll
        for (int f = 0; f < 4; ++f) {
            short8 b = *(const short8*)(lds + 32768 + (f * 16 + (l & 15)) * 512 + ((q ^ r7) << 4));
            acc[f] = __builtin_amdgcn_mfma_f32_16x16x32_bf16(a, b, acc[f], 0, 0, 0);
        }
    }
    // C/D: col = l&15, row = (l>>4)*4 + r
    const int nb = n0 + w * 16 + ((l >> 4) << 2);
    const int jb = j0 + (l & 15);
#pragma unroll
    for (int f = 0; f < 4; ++f)
#pragma unroll
        for (int r = 0; r < 4; ++r)
            h[(size_t)(nb + r) * 256 + jb + f * 16] = f2b(acc[f][r]);
}

// ---------------------------------------------------------------------------
// K2: attention scores (h is bf16)
// ---------------------------------------------------------------------------
__global__ __launch_bounds__(256) void att_scores(const unsigned short* __restrict__ h,
                                                  const float* __restrict__ att_src,
                                                  const float* __restrict__ att_dst,
                                                  float* __restrict__ as_,
                                                  float* __restrict__ ad_) {
    const int wave = threadIdx.x >> 6;
    const int lane = threadIdx.x & 63;
    const int n = blockIdx.x * 4 + wave;
    const unsigned short* hr = h + (size_t)n * 256;
    float h0 = bf2f(hr[lane]), h1 = bf2f(hr[lane + 64]);
    float h2 = bf2f(hr[lane + 128]), h3 = bf2f(hr[lane + 192]);
    float s0 = h0 * att_src[lane]       + h1 * att_src[lane + 64];
    float s1 = h2 * att_src[lane + 128] + h3 * att_src[lane + 192];
    float d0 = h0 * att_dst[lane]       + h1 * att_dst[lane + 64];
    float d1 = h2 * att_dst[lane + 128] + h3 * att_dst[lane + 192];
#pragma unroll
    for (int off = 32; off > 0; off >>= 1) {
        s0 += __shfl_down(s0, off);
        s1 += __shfl_down(s1, off);
        d0 += __shfl_down(d0, off);
        d1 += __shfl_down(d1, off);
    }
    if (lane == 0) {
        as_[n * 2] = s0; as_[n * 2 + 1] = s1;
        ad_[n * 2] = d0; ad_[n * 2 + 1] = d1;
    }
}

// ---------------------------------------------------------------------------
// K3: space GAT gather (h bf16 -> xs f32)
// ---------------------------------------------------------------------------
__global__ __launch_bounds__(256) void space_gather(const unsigned short* __restrict__ h,
                                                    const float* __restrict__ as_,
                                                    const float* __restrict__ ad_,
                                                    const int* __restrict__ esrc,
                                                    const float* __restrict__ bias,
                                                    float* __restrict__ xs) {
    __shared__ int   s_src[10];
    __shared__ float s_e[10][2];
    const int n = blockIdx.x;
    const int t = threadIdx.x;
    if (t < 10) {
        int src = (t < 9) ? esrc[(size_t)n * KNN + t] : n;
        s_src[t] = src;
        float ad0 = ad_[n * 2], ad1 = ad_[n * 2 + 1];
        float e0 = as_[src * 2]     + ad0;
        float e1 = as_[src * 2 + 1] + ad1;
        s_e[t][0] = e0 >= 0.f ? e0 : 0.2f * e0;
        s_e[t][1] = e1 >= 0.f ? e1 : 0.2f * e1;
    }
    __syncthreads();
    const int head = t >> 7;
    float m = -1e30f;
#pragma unroll
    for (int k = 0; k < 10; ++k) m = fmaxf(m, s_e[k][head]);
    float wt[10];
    float ssum = 0.f;
#pragma unroll
    for (int k = 0; k < 10; ++k) { wt[k] = __expf(s_e[k][head] - m); ssum += wt[k]; }
    const float inv = 1.f / (ssum + 1e-16f);
    float out = 0.f;
#pragma unroll
    for (int k = 0; k < 10; ++k) out += wt[k] * bf2f(h[(size_t)s_src[k] * 256 + t]);
    xs[(size_t)n * 256 + t] = out * inv + bias[t];
}

// ---------------------------------------------------------------------------
// K4: pool partials -> atomicAdd into zeroed emb (sum; scaled on read)
// ---------------------------------------------------------------------------
__global__ __launch_bounds__(256) void pool_partial(const float* __restrict__ xs,
                                                    float* __restrict__ emb) {
    const int b = blockIdx.x, ch = blockIdx.y, j = threadIdx.x;
    const float* base = xs + ((size_t)b * PGRID + ch * 64) * 256 + j;
    float s = 0.f;
#pragma unroll 8
    for (int p = 0; p < 64; ++p) s += base[p * 256];
    atomicAdd(&emb[b * 256 + j], s);
}

// ---------------------------------------------------------------------------
// K5: view linear + scalar scores (emb holds SUMS; scale by 1/576 on read)
// ---------------------------------------------------------------------------
__global__ __launch_bounds__(256) void view_linear(const float* __restrict__ emb,
                                                   const float* __restrict__ Wv,
                                                   const float* __restrict__ att_s,
                                                   const float* __restrict__ att_d,
                                                   float* __restrict__ hv,
                                                   float* __restrict__ asv,
                                                   float* __restrict__ adv) {
    __shared__ float er[256];
    __shared__ float red[2][256];
    const int i = blockIdx.x;
    const int j = threadIdx.x;
    er[j] = emb[(i % 64) * 256 + j] * (1.f / 576.f);
    __syncthreads();
    float acc = 0.f;
    for (int c = 0; c < 256; ++c) acc += er[c] * Wv[c * 256 + j];
    hv[(size_t)i * 256 + j] = acc;
    red[0][j] = acc * att_s[j];
    red[1][j] = acc * att_d[j];
    __syncthreads();
    for (int off = 128; off > 0; off >>= 1) {
        if (j < off) { red[0][j] += red[0][j + off]; red[1][j] += red[1][j + off]; }
        __syncthreads();
    }
    if (j == 0) { asv[i] = red[0][0]; adv[i] = red[1][0]; }
}

// ---------------------------------------------------------------------------
// K6: view GAT gather for dst 0..63
// ---------------------------------------------------------------------------
__global__ __launch_bounds__(256) void view_gather(const float* __restrict__ hv,
                                                   const float* __restrict__ asv,
                                                   const float* __restrict__ adv,
                                                   const int* __restrict__ ev,
                                                   int Ev,
                                                   const float* __restrict__ bias,
                                                   float* __restrict__ feat) {
    __shared__ int cnt;
    __shared__ int s_src[32];
    const int d = blockIdx.x;
    const int t = threadIdx.x;
    if (t == 0) cnt = 0;
    __syncthreads();
    for (int e = t; e < Ev; e += 256) {
        if (ev[Ev + e] == d) {
            int pos = atomicAdd(&cnt, 1);
            s_src[pos] = ev[e];
        }
    }
    __syncthreads();
    const int ns = cnt;
    const float adval = adv[d];
    float m = -1e30f;
    float ev_[16];
#pragma unroll 1
    for (int k = 0; k < ns; ++k) {
        float e = asv[s_src[k]] + adval;
        e = e >= 0.f ? e : 0.2f * e;
        ev_[k] = e;
        m = fmaxf(m, e);
    }
    float eself = asv[d] + adval;
    eself = eself >= 0.f ? eself : 0.2f * eself;
    m = fmaxf(m, eself);
    float ssum = 0.f;
#pragma unroll 1
    for (int k = 0; k < ns; ++k) { ev_[k] = __expf(ev_[k] - m); ssum += ev_[k]; }
    float wself = __expf(eself - m);
    ssum += wself;
    const float inv = 1.f / (ssum + 1e-16f);
    float out = 0.f;
#pragma unroll 1
    for (int k = 0; k < ns; ++k) out += ev_[k] * hv[(size_t)s_src[k] * 256 + t];
    out += wself * hv[(size_t)d * 256 + t];
    feat[d * 256 + t] = out * inv + bias[t];
}

// ---------------------------------------------------------------------------
// K7: out = 0.5*x_space + 0.5*feat[b]
// ---------------------------------------------------------------------------
__global__ __launch_bounds__(256) void combine(const float* __restrict__ xs,
                                               const float* __restrict__ feat,
                                               float* __restrict__ out, int ntot4) {
    int i = blockIdx.x * blockDim.x + threadIdx.x;
    if (i >= ntot4) return;
    size_t f = (size_t)i * 4;
    int b = (int)(f / (PGRID * 256));
    int j = (int)(f & 255);
    float4 a  = *(const float4*)(xs + f);
    float4 fb = *(const float4*)(feat + b * 256 + j);
    float4 o;
    o.x = 0.5f * (a.x + fb.x);
    o.y = 0.5f * (a.y + fb.y);
    o.z = 0.5f * (a.z + fb.z);
    o.w = 0.5f * (a.w + fb.w);
    *(float4*)(out + f) = o;
}

// ---------------------------------------------------------------------------
extern "C" void kernel_launch(void* const* d_in, const int* in_sizes, int n_in,
                              void* d_out, int out_size, void* d_ws, size_t ws_size,
                              hipStream_t stream) {
    const float* x        = (const float*)d_in[0];
    const int*   e_space  = (const int*)d_in[3];
    const int*   e_view   = (const int*)d_in[4];
    const float* W_space  = (const float*)d_in[5];
    const float* att_ss   = (const float*)d_in[6];
    const float* att_ds   = (const float*)d_in[7];
    const float* bias_s   = (const float*)d_in[8];
    const float* W_view   = (const float*)d_in[9];
    const float* att_sv   = (const float*)d_in[10];
    const float* att_dv   = (const float*)d_in[11];
    const float* bias_v   = (const float*)d_in[12];
    float* out = (float*)d_out;

    const int Ev = in_sizes[4] / 2;

    // workspace layout (bytes)
    char* ws = (char*)d_ws;
    unsigned short* hbf = (unsigned short*)ws;                       // 18.9 MB
    unsigned short* xbf = (unsigned short*)(ws + 18874368);          // 18.9 MB
    unsigned short* Wt  = (unsigned short*)(ws + 2 * 18874368);      // 128 KB
    float* xs   = (float*)(ws + 2 * 18874368 + 131072);              // 37.7 MB
    float* as_  = xs  + (size_t)NNODE * 256;                         // 144 KB
    float* ad_  = as_ + NNODE * 2;
    float* emb  = ad_ + NNODE * 2;                                   // 64 KB
    float* hv   = emb + 64 * 256;
    float* asv  = hv  + 128 * 256;
    float* adv  = asv + 128;
    float* feat = adv + 128;

    prep_w<<<dim3(4, 4), 256, 0, stream>>>(W_space, Wt);
    prep_x<<<dim3(9, 4, 64), 256, 0, stream>>>(x, xbf);
    gemm_mfma<<<dim3(NNODE / 64, 4), 256, 0, stream>>>(xbf, Wt, hbf);
    att_scores<<<NNODE / 4, 256, 0, stream>>>(hbf, att_ss, att_ds, as_, ad_);
    space_gather<<<NNODE, 256, 0, stream>>>(hbf, as_, ad_, e_space, bias_s, xs);
    hipMemsetAsync(emb, 0, 64 * 256 * sizeof(float), stream);
    pool_partial<<<dim3(64, 9), 256, 0, stream>>>(xs, emb);
    view_linear<<<NBTOT, 256, 0, stream>>>(emb, W_view, att_sv, att_dv, hv, asv, adv);
    view_gather<<<NB0, 256, 0, stream>>>(hv, asv, adv, e_view, Ev, bias_v, feat);

    const int ntot4 = NB0 * PGRID * 256 / 4;
    combine<<<(ntot4 + 255) / 256, 256, 0, stream>>>(xs, feat, out, ntot4);
}

// Round 4
// 216.692 us; speedup vs baseline: 1.4800x; 1.1179x over previous
//
#include <hip/hip_runtime.h>

#define PGRID 576
#define NB0   64
#define CIN   256
#define KNN   9
#define NNODE (NB0 * PGRID)   // 36864

typedef __attribute__((ext_vector_type(8))) short short8;
typedef __attribute__((ext_vector_type(4))) float f32x4;

__device__ __forceinline__ float bf2f(unsigned short u) {
    union { unsigned int i; float f; } v; v.i = ((unsigned int)u) << 16; return v.f;
}
__device__ __forceinline__ unsigned short f2b(float f) {
    unsigned int u = __float_as_uint(f);
    return (unsigned short)((u + 0x7FFFu + ((u >> 16) & 1u)) >> 16);
}

// ---------------------------------------------------------------------------
// P1: Wt[j][c] = bf16(W[c][j])   (j-major, c contiguous)
// ---------------------------------------------------------------------------
__global__ __launch_bounds__(256) void prep_w(const float* __restrict__ W,
                                              unsigned short* __restrict__ Wt) {
    __shared__ float tile[64][65];
    const int c0 = blockIdx.x * 64, j0 = blockIdx.y * 64;
    const int t = threadIdx.x, lo = t % 64, hi = t / 64;
#pragma unroll
    for (int r = 0; r < 16; ++r)
        tile[r * 4 + hi][lo] = W[(size_t)(c0 + r * 4 + hi) * 256 + j0 + lo];
    __syncthreads();
#pragma unroll
    for (int r = 0; r < 16; ++r)
        Wt[(size_t)(j0 + r * 4 + hi) * 256 + c0 + lo] = f2b(tile[lo][r * 4 + hi]);
}

// ---------------------------------------------------------------------------
// K1: fused GEMM + att-score epilogue.
// Grid 576 blocks (one per 64-row p-chunk). BM=64, BN=256 (all j), K=256 in
// two 128-c chunks. A: direct f32 global->reg->bf16 (read once). B: LDS 64KB
// per chunk, granule-XOR swizzle via pre-swizzled global_load_lds source.
// Epilogue: h bf16 write + exact per-node a_s/a_d via in-wave shfl reduce.
// ---------------------------------------------------------------------------
__global__ __launch_bounds__(256) void gemm_fused(
    const float* __restrict__ x, const unsigned short* __restrict__ Wt,
    const float* __restrict__ att_src, const float* __restrict__ att_dst,
    unsigned short* __restrict__ h, float* __restrict__ as_, float* __restrict__ ad_) {
    __shared__ char ldsB[65536];
    const int bx = blockIdx.x;
    const int t  = threadIdx.x;
    const int b  = bx / 9;
    const int p0 = (bx % 9) * 64;
    const int n0 = bx * 64;
    const int l = t & 63, w = t >> 6;
    const int l4 = l >> 4, l15 = l & 15;
    const float* xb = x + (size_t)b * (CIN * PGRID);

    // ---- stage B chunk 0 (c in [0,128)): LDS[j][g] = Wt[j][g^(j&7) granule]
    {
        const int jrow = t >> 4, g = t & 15;
#pragma unroll
        for (int i = 0; i < 16; ++i) {
            int j  = i * 16 + jrow;
            int gs = (g & 8) | ((g & 7) ^ (j & 7));
            __builtin_amdgcn_global_load_lds(
                (const char*)Wt + (size_t)j * 512 + gs * 16,
                ldsB + i * 4096 + (t & 192) * 16, 16, 0, 0);
        }
    }
    // ---- A loads (both chunks) straight from x, then pack to bf16 frags
    const int prow = p0 + w * 16 + l15;
    float a0[64];
#pragma unroll
    for (int ch = 0; ch < 2; ++ch)
#pragma unroll
        for (int q = 0; q < 4; ++q)
#pragma unroll
            for (int jj = 0; jj < 8; ++jj) {
                int c = ch * 128 + q * 32 + l4 * 8 + jj;
                a0[ch * 32 + q * 8 + jj] = xb[(size_t)c * PGRID + prow];
            }
    short8 apk[8];
#pragma unroll
    for (int cq = 0; cq < 8; ++cq) {
        short8 v;
#pragma unroll
        for (int jj = 0; jj < 8; ++jj) v[jj] = (short)f2b(a0[cq * 8 + jj]);
        apk[cq] = v;
    }
    f32x4 acc[16] = {};
    __syncthreads();                       // B0 staged (barrier drains vmcnt)
#pragma unroll
    for (int q = 0; q < 4; ++q) {
        const int gr = q * 4 + l4;
#pragma unroll
        for (int f = 0; f < 16; ++f) {
            int j  = f * 16 + l15;
            int gp = (gr & 8) | ((gr & 7) ^ (j & 7));
            short8 bf = *(const short8*)(ldsB + j * 256 + gp * 16);
            acc[f] = __builtin_amdgcn_mfma_f32_16x16x32_bf16(apk[q], bf, acc[f], 0, 0, 0);
        }
    }
    __syncthreads();                       // all waves done reading B0
    // ---- stage B chunk 1 (c in [128,256))
    {
        const int jrow = t >> 4, g = t & 15;
#pragma unroll
        for (int i = 0; i < 16; ++i) {
            int j  = i * 16 + jrow;
            int gs = (g & 8) | ((g & 7) ^ (j & 7));
            __builtin_amdgcn_global_load_lds(
                (const char*)Wt + (size_t)j * 512 + 256 + gs * 16,
                ldsB + i * 4096 + (t & 192) * 16, 16, 0, 0);
        }
    }
    __syncthreads();                       // B1 staged
#pragma unroll
    for (int q = 0; q < 4; ++q) {
        const int gr = q * 4 + l4;
#pragma unroll
        for (int f = 0; f < 16; ++f) {
            int j  = f * 16 + l15;
            int gp = (gr & 8) | ((gr & 7) ^ (j & 7));
            short8 bf = *(const short8*)(ldsB + j * 256 + gp * 16);
            acc[f] = __builtin_amdgcn_mfma_f32_16x16x32_bf16(apk[4 + q], bf, acc[f], 0, 0, 0);
        }
    }
    // ---- epilogue: h bf16 write
    const int nb = n0 + w * 16 + l4 * 4;
#pragma unroll
    for (int f = 0; f < 16; ++f)
#pragma unroll
        for (int r = 0; r < 4; ++r)
            h[(size_t)(nb + r) * 256 + l15 + f * 16] = f2b(acc[f][r]);

    // ---- epilogue: exact a_s/a_d (head0 = f<8, head1 = f>=8)
    float av[16], dvv[16];
#pragma unroll
    for (int f = 0; f < 16; ++f) {
        av[f]  = att_src[f * 16 + l15];
        dvv[f] = att_dst[f * 16 + l15];
    }
#pragma unroll
    for (int r = 0; r < 4; ++r) {
        float s0 = 0.f, s1 = 0.f, d0 = 0.f, d1 = 0.f;
#pragma unroll
        for (int f = 0; f < 8; ++f)  { s0 += acc[f][r] * av[f];  d0 += acc[f][r] * dvv[f]; }
#pragma unroll
        for (int f = 8; f < 16; ++f) { s1 += acc[f][r] * av[f];  d1 += acc[f][r] * dvv[f]; }
#pragma unroll
        for (int m = 1; m < 16; m <<= 1) {
            s0 += __shfl_xor(s0, m); s1 += __shfl_xor(s1, m);
            d0 += __shfl_xor(d0, m); d1 += __shfl_xor(d1, m);
        }
        if (l15 == 0) {
            int n = nb + r;
            as_[n * 2] = s0; as_[n * 2 + 1] = s1;
            ad_[n * 2] = d0; ad_[n * 2 + 1] = d1;
        }
    }
}

// ---------------------------------------------------------------------------
// K3: space GAT gather — 2 nodes/block, short2 h-loads (4B/lane)
// ---------------------------------------------------------------------------
__global__ __launch_bounds__(256) void space_gather(
    const unsigned short* __restrict__ h, const float* __restrict__ as_,
    const float* __restrict__ ad_, const int* __restrict__ esrc,
    const float* __restrict__ bias, float* __restrict__ xs) {
    __shared__ int   s_src[2][10];
    __shared__ float s_e[2][10][2];
    const int t = threadIdx.x;
    const int node = t >> 7;          // 0 or 1
    const int idx  = t & 127;
    const int n = blockIdx.x * 2 + node;
    if (idx < 10) {
        int src = (idx < 9) ? esrc[(size_t)n * KNN + idx] : n;
        s_src[node][idx] = src;
        float e0 = as_[src * 2]     + ad_[n * 2];
        float e1 = as_[src * 2 + 1] + ad_[n * 2 + 1];
        s_e[node][idx][0] = e0 >= 0.f ? e0 : 0.2f * e0;
        s_e[node][idx][1] = e1 >= 0.f ? e1 : 0.2f * e1;
    }
    __syncthreads();
    const int j2 = idx * 2;
    const int head = idx >> 6;
    float m = -1e30f;
#pragma unroll
    for (int k = 0; k < 10; ++k) m = fmaxf(m, s_e[node][k][head]);
    float wgt[10]; float ssum = 0.f;
#pragma unroll
    for (int k = 0; k < 10; ++k) { wgt[k] = __expf(s_e[node][k][head] - m); ssum += wgt[k]; }
    const float inv = 1.f / (ssum + 1e-16f);
    float o0 = 0.f, o1 = 0.f;
#pragma unroll
    for (int k = 0; k < 10; ++k) {
        unsigned int v = *(const unsigned int*)(h + (size_t)s_src[node][k] * 256 + j2);
        o0 += wgt[k] * bf2f((unsigned short)(v & 0xffff));
        o1 += wgt[k] * bf2f((unsigned short)(v >> 16));
    }
    float2 res;
    res.x = o0 * inv + bias[j2];
    res.y = o1 * inv + bias[j2 + 1];
    *(float2*)(xs + (size_t)n * 256 + j2) = res;
}

// ---------------------------------------------------------------------------
// K4: pool partials — 4 segments of 144 rows each, float4, no atomics
// ---------------------------------------------------------------------------
__global__ __launch_bounds__(256) void pool_partial(const float* __restrict__ xs,
                                                    float* __restrict__ embp) {
    const int b   = blockIdx.x;
    const int f4  = threadIdx.x & 63;
    const int seg = threadIdx.x >> 6;
    const float* base = xs + ((size_t)b * PGRID + seg * 144) * 256 + f4 * 4;
    float4 s = {0.f, 0.f, 0.f, 0.f};
    for (int p = 0; p < 144; ++p) {
        float4 v = *(const float4*)(base + (size_t)p * 256);
        s.x += v.x; s.y += v.y; s.z += v.z; s.w += v.w;
    }
    *(float4*)(embp + ((size_t)b * 4 + seg) * 256 + f4 * 4) = s;
}

// ---------------------------------------------------------------------------
// K5: view linear + scalar scores (embp holds 4 partial SUMS per image)
// ---------------------------------------------------------------------------
__global__ __launch_bounds__(256) void view_linear(const float* __restrict__ embp,
                                                   const float* __restrict__ Wv,
                                                   const float* __restrict__ att_s,
                                                   const float* __restrict__ att_d,
                                                   float* __restrict__ hv,
                                                   float* __restrict__ asv,
                                                   float* __restrict__ adv) {
    __shared__ float er[256];
    __shared__ float red[2][256];
    const int i = blockIdx.x;
    const int j = threadIdx.x;
    const int i64 = i & 63;
    er[j] = (embp[((size_t)i64 * 4 + 0) * 256 + j] + embp[((size_t)i64 * 4 + 1) * 256 + j] +
             embp[((size_t)i64 * 4 + 2) * 256 + j] + embp[((size_t)i64 * 4 + 3) * 256 + j]) *
            (1.f / 576.f);
    __syncthreads();
    float acc = 0.f;
    for (int c = 0; c < 256; ++c) acc += er[c] * Wv[c * 256 + j];
    hv[(size_t)i * 256 + j] = acc;
    red[0][j] = acc * att_s[j];
    red[1][j] = acc * att_d[j];
    __syncthreads();
    for (int off = 128; off > 0; off >>= 1) {
        if (j < off) { red[0][j] += red[0][j + off]; red[1][j] += red[1][j + off]; }
        __syncthreads();
    }
    if (j == 0) { asv[i] = red[0][0]; adv[i] = red[1][0]; }
}

// ---------------------------------------------------------------------------
// K6: view GAT gather for dst 0..63
// ---------------------------------------------------------------------------
__global__ __launch_bounds__(256) void view_gather(const float* __restrict__ hv,
                                                   const float* __restrict__ asv,
                                                   const float* __restrict__ adv,
                                                   const int* __restrict__ ev,
                                                   int Ev,
                                                   const float* __restrict__ bias,
                                                   float* __restrict__ feat) {
    __shared__ int cnt;
    __shared__ int s_src[32];
    const int d = blockIdx.x;
    const int t = threadIdx.x;
    if (t == 0) cnt = 0;
    __syncthreads();
    for (int e = t; e < Ev; e += 256) {
        if (ev[Ev + e] == d) {
            int pos = atomicAdd(&cnt, 1);
            s_src[pos] = ev[e];
        }
    }
    __syncthreads();
    const int ns = cnt;
    const float adval = adv[d];
    float m = -1e30f;
    float ev_[16];
#pragma unroll 1
    for (int k = 0; k < ns; ++k) {
        float e = asv[s_src[k]] + adval;
        e = e >= 0.f ? e : 0.2f * e;
        ev_[k] = e;
        m = fmaxf(m, e);
    }
    float eself = asv[d] + adval;
    eself = eself >= 0.f ? eself : 0.2f * eself;
    m = fmaxf(m, eself);
    float ssum = 0.f;
#pragma unroll 1
    for (int k = 0; k < ns; ++k) { ev_[k] = __expf(ev_[k] - m); ssum += ev_[k]; }
    float wself = __expf(eself - m);
    ssum += wself;
    const float inv = 1.f / (ssum + 1e-16f);
    float out = 0.f;
#pragma unroll 1
    for (int k = 0; k < ns; ++k) out += ev_[k] * hv[(size_t)s_src[k] * 256 + t];
    out += wself * hv[(size_t)d * 256 + t];
    feat[d * 256 + t] = out * inv + bias[t];
}

// ---------------------------------------------------------------------------
// K7: out = 0.5*x_space + 0.5*feat[b]
// ---------------------------------------------------------------------------
__global__ __launch_bounds__(256) void combine(const float* __restrict__ xs,
                                               const float* __restrict__ feat,
                                               float* __restrict__ out, int ntot4) {
    int i = blockIdx.x * blockDim.x + threadIdx.x;
    if (i >= ntot4) return;
    size_t f = (size_t)i * 4;
    int b = (int)(f / (PGRID * 256));
    int j = (int)(f & 255);
    float4 a  = *(const float4*)(xs + f);
    float4 fb = *(const float4*)(feat + b * 256 + j);
    float4 o;
    o.x = 0.5f * (a.x + fb.x);
    o.y = 0.5f * (a.y + fb.y);
    o.z = 0.5f * (a.z + fb.z);
    o.w = 0.5f * (a.w + fb.w);
    *(float4*)(out + f) = o;
}

// ---------------------------------------------------------------------------
extern "C" void kernel_launch(void* const* d_in, const int* in_sizes, int n_in,
                              void* d_out, int out_size, void* d_ws, size_t ws_size,
                              hipStream_t stream) {
    const float* x        = (const float*)d_in[0];
    const int*   e_space  = (const int*)d_in[3];
    const int*   e_view   = (const int*)d_in[4];
    const float* W_space  = (const float*)d_in[5];
    const float* att_ss   = (const float*)d_in[6];
    const float* att_ds   = (const float*)d_in[7];
    const float* bias_s   = (const float*)d_in[8];
    const float* W_view   = (const float*)d_in[9];
    const float* att_sv   = (const float*)d_in[10];
    const float* att_dv   = (const float*)d_in[11];
    const float* bias_v   = (const float*)d_in[12];
    float* out = (float*)d_out;

    const int Ev = in_sizes[4] / 2;

    // workspace layout (bytes)
    char* ws = (char*)d_ws;
    unsigned short* hbf = (unsigned short*)ws;                       // 18.9 MB
    unsigned short* Wt  = (unsigned short*)(ws + 18874368);          // 128 KB
    float* xs   = (float*)(ws + 18874368 + 131072);                  // 37.7 MB
    float* as_  = xs  + (size_t)NNODE * 256;
    float* ad_  = as_ + NNODE * 2;
    float* embp = ad_ + NNODE * 2;                                   // 64*4*256
    float* hv   = embp + 64 * 4 * 256;
    float* asv  = hv  + 128 * 256;
    float* adv  = asv + 128;
    float* feat = adv + 128;

    prep_w<<<dim3(4, 4), 256, 0, stream>>>(W_space, Wt);
    gemm_fused<<<576, 256, 0, stream>>>(x, Wt, att_ss, att_ds, hbf, as_, ad_);
    space_gather<<<NNODE / 2, 256, 0, stream>>>(hbf, as_, ad_, e_space, bias_s, xs);
    pool_partial<<<NB0, 256, 0, stream>>>(xs, embp);
    view_linear<<<128, 256, 0, stream>>>(embp, W_view, att_sv, att_dv, hv, asv, adv);
    view_gather<<<NB0, 256, 0, stream>>>(hv, asv, adv, e_view, Ev, bias_v, feat);

    const int ntot4 = NB0 * PGRID * 256 / 4;
    combine<<<(ntot4 + 255) / 256, 256, 0, stream>>>(xs, feat, out, ntot4);
}

// Round 5
// 209.866 us; speedup vs baseline: 1.5282x; 1.0325x over previous
//
#include <hip/hip_runtime.h>

#define PGRID 576
#define NB0   64
#define CIN   256
#define KNN   9
#define NNODE (NB0 * PGRID)   // 36864

typedef __attribute__((ext_vector_type(8))) short short8;
typedef __attribute__((ext_vector_type(4))) float f32x4;

__device__ __forceinline__ float bf2f(unsigned short u) {
    union { unsigned int i; float f; } v; v.i = ((unsigned int)u) << 16; return v.f;
}
__device__ __forceinline__ unsigned short f2b(float f) {
    unsigned int u = __float_as_uint(f);
    return (unsigned short)((u + 0x7FFFu + ((u >> 16) & 1u)) >> 16);
}

// ---------------------------------------------------------------------------
// P1: Wt[j][c] = bf16(W[c][j])
// ---------------------------------------------------------------------------
__global__ __launch_bounds__(256) void prep_w(const float* __restrict__ W,
                                              unsigned short* __restrict__ Wt) {
    __shared__ float tile[64][65];
    const int c0 = blockIdx.x * 64, j0 = blockIdx.y * 64;
    const int t = threadIdx.x, lo = t % 64, hi = t / 64;
#pragma unroll
    for (int r = 0; r < 16; ++r)
        tile[r * 4 + hi][lo] = W[(size_t)(c0 + r * 4 + hi) * 256 + j0 + lo];
    __syncthreads();
#pragma unroll
    for (int r = 0; r < 16; ++r)
        Wt[(size_t)(j0 + r * 4 + hi) * 256 + c0 + lo] = f2b(tile[lo][r * 4 + hi]);
}

// ---------------------------------------------------------------------------
// K1: fused GEMM + att-score epilogue (BM=64, BN=256, K=256 in 2 chunks).
// A: direct f32 global->reg->bf16 (read once, issued first: HBM latency).
// B: 64KB LDS per chunk via granule-XOR pre-swizzled global_load_lds.
// ---------------------------------------------------------------------------
__global__ __launch_bounds__(256) void gemm_fused(
    const float* __restrict__ x, const unsigned short* __restrict__ Wt,
    const float* __restrict__ att_src, const float* __restrict__ att_dst,
    unsigned short* __restrict__ h, float* __restrict__ as_, float* __restrict__ ad_) {
    __shared__ char ldsB[65536];
    const int bx = blockIdx.x;
    const int t  = threadIdx.x;
    const int b  = bx / 9;
    const int p0 = (bx % 9) * 64;
    const int n0 = bx * 64;
    const int l = t & 63, w = t >> 6;
    const int l4 = l >> 4, l15 = l & 15;
    const float* xb = x + (size_t)b * (CIN * PGRID);

    // ---- A loads (both chunks) straight from x — issue first (HBM latency)
    const int prow = p0 + w * 16 + l15;
    float a0[64];
#pragma unroll
    for (int ch = 0; ch < 2; ++ch)
#pragma unroll
        for (int q = 0; q < 4; ++q)
#pragma unroll
            for (int jj = 0; jj < 8; ++jj) {
                int c = ch * 128 + q * 32 + l4 * 8 + jj;
                a0[ch * 32 + q * 8 + jj] = xb[(size_t)c * PGRID + prow];
            }
    // ---- stage B chunk 0 (c in [0,128))
    {
        const int jrow = t >> 4, g = t & 15;
#pragma unroll
        for (int i = 0; i < 16; ++i) {
            int j  = i * 16 + jrow;
            int gs = (g & 8) | ((g & 7) ^ (j & 7));
            __builtin_amdgcn_global_load_lds(
                (const char*)Wt + (size_t)j * 512 + gs * 16,
                ldsB + i * 4096 + (t & 192) * 16, 16, 0, 0);
        }
    }
    short8 apk[8];
#pragma unroll
    for (int cq = 0; cq < 8; ++cq) {
        short8 v;
#pragma unroll
        for (int jj = 0; jj < 8; ++jj) v[jj] = (short)f2b(a0[cq * 8 + jj]);
        apk[cq] = v;
    }
    f32x4 acc[16] = {};
    __syncthreads();                       // B0 staged
#pragma unroll
    for (int q = 0; q < 4; ++q) {
        const int gr = q * 4 + l4;
#pragma unroll
        for (int f = 0; f < 16; ++f) {
            int j  = f * 16 + l15;
            int gp = (gr & 8) | ((gr & 7) ^ (j & 7));
            short8 bf = *(const short8*)(ldsB + j * 256 + gp * 16);
            acc[f] = __builtin_amdgcn_mfma_f32_16x16x32_bf16(apk[q], bf, acc[f], 0, 0, 0);
        }
    }
    __syncthreads();                       // all waves done reading B0
    // ---- stage B chunk 1 (c in [128,256))
    {
        const int jrow = t >> 4, g = t & 15;
#pragma unroll
        for (int i = 0; i < 16; ++i) {
            int j  = i * 16 + jrow;
            int gs = (g & 8) | ((g & 7) ^ (j & 7));
            __builtin_amdgcn_global_load_lds(
                (const char*)Wt + (size_t)j * 512 + 256 + gs * 16,
                ldsB + i * 4096 + (t & 192) * 16, 16, 0, 0);
        }
    }
    __syncthreads();                       // B1 staged
#pragma unroll
    for (int q = 0; q < 4; ++q) {
        const int gr = q * 4 + l4;
#pragma unroll
        for (int f = 0; f < 16; ++f) {
            int j  = f * 16 + l15;
            int gp = (gr & 8) | ((gr & 7) ^ (j & 7));
            short8 bf = *(const short8*)(ldsB + j * 256 + gp * 16);
            acc[f] = __builtin_amdgcn_mfma_f32_16x16x32_bf16(apk[4 + q], bf, acc[f], 0, 0, 0);
        }
    }
    // ---- epilogue: h bf16 write
    const int nb = n0 + w * 16 + l4 * 4;
#pragma unroll
    for (int f = 0; f < 16; ++f)
#pragma unroll
        for (int r = 0; r < 4; ++r)
            h[(size_t)(nb + r) * 256 + l15 + f * 16] = f2b(acc[f][r]);

    // ---- epilogue: exact a_s/a_d
    float av[16], dvv[16];
#pragma unroll
    for (int f = 0; f < 16; ++f) {
        av[f]  = att_src[f * 16 + l15];
        dvv[f] = att_dst[f * 16 + l15];
    }
#pragma unroll
    for (int r = 0; r < 4; ++r) {
        float s0 = 0.f, s1 = 0.f, d0 = 0.f, d1 = 0.f;
#pragma unroll
        for (int f = 0; f < 8; ++f)  { s0 += acc[f][r] * av[f];  d0 += acc[f][r] * dvv[f]; }
#pragma unroll
        for (int f = 8; f < 16; ++f) { s1 += acc[f][r] * av[f];  d1 += acc[f][r] * dvv[f]; }
#pragma unroll
        for (int m = 1; m < 16; m <<= 1) {
            s0 += __shfl_xor(s0, m); s1 += __shfl_xor(s1, m);
            d0 += __shfl_xor(d0, m); d1 += __shfl_xor(d1, m);
        }
        if (l15 == 0) {
            int n = nb + r;
            as_[n * 2] = s0; as_[n * 2 + 1] = s1;
            ad_[n * 2] = d0; ad_[n * 2 + 1] = d1;
        }
    }
}

// ---------------------------------------------------------------------------
// K3: space GAT gather — 2 nodes/block; writes xs as bf16 (packed uint)
// ---------------------------------------------------------------------------
__global__ __launch_bounds__(256) void space_gather(
    const unsigned short* __restrict__ h, const float* __restrict__ as_,
    const float* __restrict__ ad_, const int* __restrict__ esrc,
    const float* __restrict__ bias, unsigned short* __restrict__ xsb) {
    __shared__ int   s_src[2][10];
    __shared__ float s_e[2][10][2];
    const int t = threadIdx.x;
    const int node = t >> 7;
    const int idx  = t & 127;
    const int n = blockIdx.x * 2 + node;
    if (idx < 10) {
        int src = (idx < 9) ? esrc[(size_t)n * KNN + idx] : n;
        s_src[node][idx] = src;
        float e0 = as_[src * 2]     + ad_[n * 2];
        float e1 = as_[src * 2 + 1] + ad_[n * 2 + 1];
        s_e[node][idx][0] = e0 >= 0.f ? e0 : 0.2f * e0;
        s_e[node][idx][1] = e1 >= 0.f ? e1 : 0.2f * e1;
    }
    __syncthreads();
    const int j2 = idx * 2;
    const int head = idx >> 6;
    float m = -1e30f;
#pragma unroll
    for (int k = 0; k < 10; ++k) m = fmaxf(m, s_e[node][k][head]);
    float wgt[10]; float ssum = 0.f;
#pragma unroll
    for (int k = 0; k < 10; ++k) { wgt[k] = __expf(s_e[node][k][head] - m); ssum += wgt[k]; }
    const float inv = 1.f / (ssum + 1e-16f);
    float o0 = 0.f, o1 = 0.f;
#pragma unroll
    for (int k = 0; k < 10; ++k) {
        unsigned int v = *(const unsigned int*)(h + (size_t)s_src[node][k] * 256 + j2);
        o0 += wgt[k] * bf2f((unsigned short)(v & 0xffff));
        o1 += wgt[k] * bf2f((unsigned short)(v >> 16));
    }
    o0 = o0 * inv + bias[j2];
    o1 = o1 * inv + bias[j2 + 1];
    unsigned int pack = (unsigned int)f2b(o0) | ((unsigned int)f2b(o1) << 16);
    *(unsigned int*)(xsb + (size_t)n * 256 + j2) = pack;
}

// ---------------------------------------------------------------------------
// K4: pool partials — grid(64,9), 64-row segments, bf16 reads, 9 partials
// ---------------------------------------------------------------------------
__global__ __launch_bounds__(256) void pool_partial(const unsigned short* __restrict__ xsb,
                                                    float* __restrict__ embp) {
    __shared__ float red[2][256];
    const int b = blockIdx.x, seg = blockIdx.y;
    const int t = threadIdx.x;
    const int j2 = (t & 127) * 2, half = t >> 7;
    const unsigned short* base = xsb + ((size_t)b * PGRID + seg * 64 + half * 32) * 256 + j2;
    float s0 = 0.f, s1 = 0.f;
#pragma unroll 8
    for (int p = 0; p < 32; ++p) {
        unsigned int v = *(const unsigned int*)(base + (size_t)p * 256);
        s0 += bf2f((unsigned short)(v & 0xffff));
        s1 += bf2f((unsigned short)(v >> 16));
    }
    red[half][j2] = s0; red[half][j2 + 1] = s1;
    __syncthreads();
    if (half == 0) {
        float2 r;
        r.x = s0 + red[1][j2];
        r.y = s1 + red[1][j2 + 1];
        *(float2*)(embp + ((size_t)b * 9 + seg) * 256 + j2) = r;
    }
}

// ---------------------------------------------------------------------------
// K5: view linear + scalar scores (embp holds 9 partial SUMS per image)
// ---------------------------------------------------------------------------
__global__ __launch_bounds__(256) void view_linear(const float* __restrict__ embp,
                                                   const float* __restrict__ Wv,
                                                   const float* __restrict__ att_s,
                                                   const float* __restrict__ att_d,
                                                   float* __restrict__ hv,
                                                   float* __restrict__ asv,
                                                   float* __restrict__ adv) {
    __shared__ float er[256];
    __shared__ float red[2][256];
    const int i = blockIdx.x;
    const int j = threadIdx.x;
    const int i64 = i & 63;
    float s = 0.f;
#pragma unroll
    for (int seg = 0; seg < 9; ++seg) s += embp[((size_t)i64 * 9 + seg) * 256 + j];
    er[j] = s * (1.f / 576.f);
    __syncthreads();
    float acc = 0.f;
    for (int c = 0; c < 256; ++c) acc += er[c] * Wv[c * 256 + j];
    hv[(size_t)i * 256 + j] = acc;
    red[0][j] = acc * att_s[j];
    red[1][j] = acc * att_d[j];
    __syncthreads();
    for (int off = 128; off > 0; off >>= 1) {
        if (j < off) { red[0][j] += red[0][j + off]; red[1][j] += red[1][j + off]; }
        __syncthreads();
    }
    if (j == 0) { asv[i] = red[0][0]; adv[i] = red[1][0]; }
}

// ---------------------------------------------------------------------------
// K6: view GAT gather for dst 0..63
// ---------------------------------------------------------------------------
__global__ __launch_bounds__(256) void view_gather(const float* __restrict__ hv,
                                                   const float* __restrict__ asv,
                                                   const float* __restrict__ adv,
                                                   const int* __restrict__ ev,
                                                   int Ev,
                                                   const float* __restrict__ bias,
                                                   float* __restrict__ feat) {
    __shared__ int cnt;
    __shared__ int s_src[32];
    const int d = blockIdx.x;
    const int t = threadIdx.x;
    if (t == 0) cnt = 0;
    __syncthreads();
    for (int e = t; e < Ev; e += 256) {
        if (ev[Ev + e] == d) {
            int pos = atomicAdd(&cnt, 1);
            s_src[pos] = ev[e];
        }
    }
    __syncthreads();
    const int ns = cnt;
    const float adval = adv[d];
    float m = -1e30f;
    float ev_[16];
#pragma unroll 1
    for (int k = 0; k < ns; ++k) {
        float e = asv[s_src[k]] + adval;
        e = e >= 0.f ? e : 0.2f * e;
        ev_[k] = e;
        m = fmaxf(m, e);
    }
    float eself = asv[d] + adval;
    eself = eself >= 0.f ? eself : 0.2f * eself;
    m = fmaxf(m, eself);
    float ssum = 0.f;
#pragma unroll 1
    for (int k = 0; k < ns; ++k) { ev_[k] = __expf(ev_[k] - m); ssum += ev_[k]; }
    float wself = __expf(eself - m);
    ssum += wself;
    const float inv = 1.f / (ssum + 1e-16f);
    float out = 0.f;
#pragma unroll 1
    for (int k = 0; k < ns; ++k) out += ev_[k] * hv[(size_t)s_src[k] * 256 + t];
    out += wself * hv[(size_t)d * 256 + t];
    feat[d * 256 + t] = out * inv + bias[t];
}

// ---------------------------------------------------------------------------
// K7: out = 0.5*xs(bf16) + 0.5*feat[b]
// ---------------------------------------------------------------------------
__global__ __launch_bounds__(256) void combine(const unsigned short* __restrict__ xsb,
                                               const float* __restrict__ feat,
                                               float* __restrict__ out, int ntot4) {
    int i = blockIdx.x * blockDim.x + threadIdx.x;
    if (i >= ntot4) return;
    size_t f = (size_t)i * 4;
    int b = (int)(f / (PGRID * 256));
    int j = (int)(f & 255);
    uint2 v = *(const uint2*)(xsb + f);
    float4 fb = *(const float4*)(feat + b * 256 + j);
    float4 o;
    o.x = 0.5f * (bf2f((unsigned short)(v.x & 0xffff)) + fb.x);
    o.y = 0.5f * (bf2f((unsigned short)(v.x >> 16))   + fb.y);
    o.z = 0.5f * (bf2f((unsigned short)(v.y & 0xffff)) + fb.z);
    o.w = 0.5f * (bf2f((unsigned short)(v.y >> 16))   + fb.w);
    *(float4*)(out + f) = o;
}

// ---------------------------------------------------------------------------
extern "C" void kernel_launch(void* const* d_in, const int* in_sizes, int n_in,
                              void* d_out, int out_size, void* d_ws, size_t ws_size,
                              hipStream_t stream) {
    const float* x        = (const float*)d_in[0];
    const int*   e_space  = (const int*)d_in[3];
    const int*   e_view   = (const int*)d_in[4];
    const float* W_space  = (const float*)d_in[5];
    const float* att_ss   = (const float*)d_in[6];
    const float* att_ds   = (const float*)d_in[7];
    const float* bias_s   = (const float*)d_in[8];
    const float* W_view   = (const float*)d_in[9];
    const float* att_sv   = (const float*)d_in[10];
    const float* att_dv   = (const float*)d_in[11];
    const float* bias_v   = (const float*)d_in[12];
    float* out = (float*)d_out;

    const int Ev = in_sizes[4] / 2;

    // workspace layout (bytes)
    char* ws = (char*)d_ws;
    unsigned short* hbf = (unsigned short*)ws;                       // 18.9 MB
    unsigned short* Wt  = (unsigned short*)(ws + 18874368);          // 128 KB
    unsigned short* xsb = (unsigned short*)(ws + 18874368 + 131072); // 18.9 MB
    float* as_  = (float*)(ws + 2 * 18874368 + 131072);
    float* ad_  = as_ + NNODE * 2;
    float* embp = ad_ + NNODE * 2;                                   // 64*9*256
    float* hv   = embp + 64 * 9 * 256;
    float* asv  = hv  + 128 * 256;
    float* adv  = asv + 128;
    float* feat = adv + 128;

    prep_w<<<dim3(4, 4), 256, 0, stream>>>(W_space, Wt);
    gemm_fused<<<576, 256, 0, stream>>>(x, Wt, att_ss, att_ds, hbf, as_, ad_);
    space_gather<<<NNODE / 2, 256, 0, stream>>>(hbf, as_, ad_, e_space, bias_s, xsb);
    pool_partial<<<dim3(NB0, 9), 256, 0, stream>>>(xsb, embp);
    view_linear<<<128, 256, 0, stream>>>(embp, W_view, att_sv, att_dv, hv, asv, adv);
    view_gather<<<NB0, 256, 0, stream>>>(hv, asv, adv, e_view, Ev, bias_v, feat);

    const int ntot4 = NB0 * PGRID * 256 / 4;
    combine<<<(ntot4 + 255) / 256, 256, 0, stream>>>(xsb, feat, out, ntot4);
}